// Round 7
// baseline (82.701 us; speedup 1.0000x reference)
//
#include <hip/hip_runtime.h>
#include <cmath>

typedef _Float16 half8 __attribute__((ext_vector_type(8)));
typedef float f32x4 __attribute__((ext_vector_type(4)));

namespace {
constexpr int BB   = 64;
constexpr int TT   = 1002;
constexpr int DD   = 8;
constexpr int HH   = 64;
constexpr int LAGS = 2;
constexpr int NW   = TT - LAGS;          // 1000
constexpr int FIN  = LAGS * DD + 1;      // 17
constexpr int NTOT = BB * NW;            // 64000
constexpr int GX   = (NW + 63) / 64;     // 16 (64 windows per block)

// output layout (flat, return order)
constexpr int RES_OFF = 0;
constexpr int LOG_OFF = NTOT * DD;
constexpr int HJ_OFF  = LOG_OFF + BB;

// prepacked A-fragment arrays in d_ws (f16 units).
// A-frag layout per (mt,kc): lane holds A[m][k], m = mt*16 + (lane&15),
// k = kc*32 + (lane>>4)*8 + j, j=0..7  -> [mt][kc][lane][8] contiguous.
constexpr int SZ_A0F = 4 * 1 * 64 * 8;   // fwd L0: A[h][f], K=32 (pad f>=17 -> 0)
constexpr int SZ_AH  = 4 * 2 * 64 * 8;   // 64x64 matrices, K=64
constexpr int SZ_A0T = 2 * 2 * 64 * 8;   // g-step: A[f][h], M=32 (pad f>=17 -> 0)
constexpr int OA0F = 0;
constexpr int OA1F = OA0F + DD * SZ_A0F; // W1 fwd
constexpr int OA2F = OA1F + DD * SZ_AH;  // W2 fwd
constexpr int OA2T = OA2F + DD * SZ_AH;  // W2^T (v1 step)
constexpr int OA1T = OA2T + DD * SZ_AH;  // W1^T (v0 step)
constexpr int OA0T = OA1T + DD * SZ_AH;  // W0^T (g step)
constexpr int WTOT = OA0T + DD * SZ_A0T; // 163840 f16 = 320 KB
}

// Prepack all weights into per-lane MFMA A-fragments (f16).
__global__ void setup_weights(const float* __restrict__ W0, const float* __restrict__ W1,
                              const float* __restrict__ W2, _Float16* __restrict__ wsp)
{
    for (int i = blockIdx.x * blockDim.x + threadIdx.x; i < WTOT;
         i += gridDim.x * blockDim.x) {
        float val;
        if (i < OA1F) {          // A0F: A[m=h][k=f] = W0[d,m,k], K=32 padded
            int j = i - OA0F, d = j / SZ_A0F, r = j % SZ_A0F;
            int mt = r / 512, r2 = r % 512, lane = r2 / 8, jj = r2 % 8;
            int m = mt * 16 + (lane & 15), k = (lane >> 4) * 8 + jj;
            val = (k < FIN) ? W0[((size_t)d * HH + m) * FIN + k] : 0.0f;
        } else if (i < OA2F) {   // A1F: A[m][k] = W1[d,m,k]
            int j = i - OA1F, d = j / SZ_AH, r = j % SZ_AH;
            int mt = r / 1024, r2 = r % 1024, kc = r2 / 512, r3 = r2 % 512;
            int lane = r3 / 8, jj = r3 % 8;
            int m = mt * 16 + (lane & 15), k = kc * 32 + (lane >> 4) * 8 + jj;
            val = W1[((size_t)d * HH + m) * HH + k];
        } else if (i < OA2T) {   // A2F: A[m][k] = W2[d,m,k]
            int j = i - OA2F, d = j / SZ_AH, r = j % SZ_AH;
            int mt = r / 1024, r2 = r % 1024, kc = r2 / 512, r3 = r2 % 512;
            int lane = r3 / 8, jj = r3 % 8;
            int m = mt * 16 + (lane & 15), k = kc * 32 + (lane >> 4) * 8 + jj;
            val = W2[((size_t)d * HH + m) * HH + k];
        } else if (i < OA1T) {   // A2T: A[m=h'][k=g] = W2[d,k,m]
            int j = i - OA2T, d = j / SZ_AH, r = j % SZ_AH;
            int mt = r / 1024, r2 = r % 1024, kc = r2 / 512, r3 = r2 % 512;
            int lane = r3 / 8, jj = r3 % 8;
            int m = mt * 16 + (lane & 15), k = kc * 32 + (lane >> 4) * 8 + jj;
            val = W2[((size_t)d * HH + k) * HH + m];
        } else if (i < OA0T) {   // A1T: A[m=h][k=h'] = W1[d,k,m]
            int j = i - OA1T, d = j / SZ_AH, r = j % SZ_AH;
            int mt = r / 1024, r2 = r % 1024, kc = r2 / 512, r3 = r2 % 512;
            int lane = r3 / 8, jj = r3 % 8;
            int m = mt * 16 + (lane & 15), k = kc * 32 + (lane >> 4) * 8 + jj;
            val = W1[((size_t)d * HH + k) * HH + m];
        } else {                 // A0T: A[m=f][k=h] = W0[d,k,m], M=32 padded
            int j = i - OA0T, d = j / SZ_A0T, r = j % SZ_A0T;
            int mt = r / 1024, r2 = r % 1024, kc = r2 / 512, r3 = r2 % 512;
            int lane = r3 / 8, jj = r3 % 8;
            int m = mt * 16 + (lane & 15), k = kc * 32 + (lane >> 4) * 8 + jj;
            val = (m < FIN) ? W0[((size_t)d * HH + k) * FIN + m] : 0.0f;
        }
        wsp[i] = (_Float16)val;
    }
}

// swizzled LDS byte address for activation tile X[n][k] (rows 128B):
// XOR bits 4-6 with (n&7) -> b128 B-reads and b64 C-writes are ~2-way (free).
__device__ __forceinline__ int swb(int n, int byteoff) {
    return n * 128 + (byteoff ^ ((n & 7) << 4));
}

// M-split 2-wave blocks: block = (window-tile, b, d), 128 threads.
// Wave w computes output rows h = 32w .. 32w+31 of every layer GEMM
// (C[2][4] = 32 VGPRs). Both waves share one 8KB activation tile;
// __syncthreads between stages. Round-6 evidence: per-wave VALU count
// (~5K inst) and serial stage latency are the limiters -> halve per-wave
// work, double wave count, cut masks to 32-bit.
__global__ __launch_bounds__(128) void fused_mlp(
    const float* __restrict__ x,
    const float* __restrict__ b0, const float* __restrict__ a0,
    const float* __restrict__ b1, const float* __restrict__ a1,
    const float* __restrict__ b2, const float* __restrict__ a2,
    const float* __restrict__ W3, const float* __restrict__ b3,
    const _Float16* __restrict__ wsp,
    float* __restrict__ out, float* __restrict__ partials)
{
    const int bx  = blockIdx.x;    // 0..GX-1
    const int b   = blockIdx.y;    // 0..BB-1
    const int d   = blockIdx.z;    // 0..DD-1
    const int tid = threadIdx.x;
    const int wv  = __builtin_amdgcn_readfirstlane(tid >> 6);  // 0..1
    const int t   = tid & 63;
    const int hi  = t >> 4, lo = t & 15;
    const int w0  = bx * 64;

    __shared__ __align__(16) unsigned char Xs[64 * 128];  // X[n][k] f16, swizzled
    __shared__ float osb[128];                            // cross-wave output partials

    // ---- build B0 rows (threads 0..63, one row each) ----
    if (tid < 64) {
        const int w = min(w0 + tid, NW - 1);
        const float* xr = x + ((size_t)b * TT + w) * DD;
        f32x4 x0 = *(const f32x4*)(xr + 0);
        f32x4 x1 = *(const f32x4*)(xr + 4);
        f32x4 x2 = *(const f32x4*)(xr + 8);
        f32x4 x3 = *(const f32x4*)(xr + 12);
        float xl = xr[2 * DD + d];
        half8 r0, r1, r2, rz;
        #pragma unroll
        for (int j = 0; j < 4; ++j) {
            r0[j] = (_Float16)x0[j]; r0[4 + j] = (_Float16)x1[j];
            r1[j] = (_Float16)x2[j]; r1[4 + j] = (_Float16)x3[j];
            r2[j] = (_Float16)0.0f;  r2[4 + j] = (_Float16)0.0f;
            rz[j] = (_Float16)0.0f;  rz[4 + j] = (_Float16)0.0f;
        }
        r2[0] = (_Float16)xl;
        *(half8*)&Xs[swb(tid, 0)]  = r0;
        *(half8*)&Xs[swb(tid, 16)] = r1;
        *(half8*)&Xs[swb(tid, 32)] = r2;
        *(half8*)&Xs[swb(tid, 48)] = rz;
    }
    __syncthreads();

    const float A0v = a0[d], A1v = a1[d], A2v = a2[d];
    f32x4 C[2][4];   // [ml][nt]: rows h = (2*wv+ml)*16 + hi*4 + r, col n = nt*16+lo

    // ---- K=64 GEMM into C (this wave's M-half) ----
    auto gemmK64 = [&](const _Float16* apk, const float* bp) {
        #pragma unroll
        for (int ml = 0; ml < 2; ++ml) {
            f32x4 bb;
            if (bp) bb = *(const f32x4*)(bp + (2 * wv + ml) * 16 + hi * 4);
            else { bb[0] = 0.f; bb[1] = 0.f; bb[2] = 0.f; bb[3] = 0.f; }
            #pragma unroll
            for (int nt = 0; nt < 4; ++nt) C[ml][nt] = bb;
        }
        #pragma unroll
        for (int kc = 0; kc < 2; ++kc) {
            half8 Bv[4];
            #pragma unroll
            for (int nt = 0; nt < 4; ++nt)
                Bv[nt] = *(const half8*)&Xs[swb(nt * 16 + lo, kc * 64 + hi * 16)];
            #pragma unroll
            for (int ml = 0; ml < 2; ++ml) {
                half8 af = *(const half8*)(apk +
                    (size_t)(((2 * wv + ml) * 2 + kc) * 64 + t) * 8);
                #pragma unroll
                for (int nt = 0; nt < 4; ++nt)
                    C[ml][nt] = __builtin_amdgcn_mfma_f32_16x16x32_f16(af, Bv[nt], C[ml][nt], 0, 0, 0);
            }
        }
    };

    // ---- store this wave's C half (as f16) into the activation tile ----
    auto storeC = [&]() {
        #pragma unroll
        for (int ml = 0; ml < 2; ++ml)
            #pragma unroll
            for (int nt = 0; nt < 4; ++nt) {
                _Float16 p0 = (_Float16)C[ml][nt][0], p1 = (_Float16)C[ml][nt][1];
                _Float16 p2 = (_Float16)C[ml][nt][2], p3 = (_Float16)C[ml][nt][3];
                unsigned int u0 = ((unsigned int)__builtin_bit_cast(unsigned short, p1) << 16)
                                 | __builtin_bit_cast(unsigned short, p0);
                unsigned int u1 = ((unsigned int)__builtin_bit_cast(unsigned short, p3) << 16)
                                 | __builtin_bit_cast(unsigned short, p2);
                uint2 pk; pk.x = u0; pk.y = u1;
                *(uint2*)&Xs[swb(nt * 16 + lo, (2 * wv + ml) * 32 + hi * 8)] = pk;
            }
    };

    unsigned int m0 = 0u, m1 = 0u, m2 = 0u;   // 32-bit masks: bit = nt*8 + ml*4 + r
    auto prelu = [&](float slope, unsigned int& mask) {
        #pragma unroll
        for (int ml = 0; ml < 2; ++ml)
            #pragma unroll
            for (int nt = 0; nt < 4; ++nt)
                #pragma unroll
                for (int r = 0; r < 4; ++r) {
                    float z = C[ml][nt][r];
                    if (z > 0.0f) mask |= 1u << (nt * 8 + ml * 4 + r);
                    C[ml][nt][r] = fmaxf(z, slope * z);  // slope=0.25 in [0,1]
                }
    };
    auto bwd_mask = [&](float slope, unsigned int mask) {
        #pragma unroll
        for (int ml = 0; ml < 2; ++ml)
            #pragma unroll
            for (int nt = 0; nt < 4; ++nt)
                #pragma unroll
                for (int r = 0; r < 4; ++r)
                    if (!((mask >> (nt * 8 + ml * 4 + r)) & 1u))
                        C[ml][nt][r] *= slope;
    };

    // ================= forward =================
    // layer 0: K=32 (single k-chunk)
    {
        #pragma unroll
        for (int ml = 0; ml < 2; ++ml) {
            f32x4 bb = *(const f32x4*)(b0 + d * HH + (2 * wv + ml) * 16 + hi * 4);
            #pragma unroll
            for (int nt = 0; nt < 4; ++nt) C[ml][nt] = bb;
        }
        half8 Bv[4];
        #pragma unroll
        for (int nt = 0; nt < 4; ++nt)
            Bv[nt] = *(const half8*)&Xs[swb(nt * 16 + lo, hi * 16)];
        const _Float16* apk = wsp + OA0F + (size_t)d * SZ_A0F;
        #pragma unroll
        for (int ml = 0; ml < 2; ++ml) {
            half8 af = *(const half8*)(apk + (size_t)((2 * wv + ml) * 64 + t) * 8);
            #pragma unroll
            for (int nt = 0; nt < 4; ++nt)
                C[ml][nt] = __builtin_amdgcn_mfma_f32_16x16x32_f16(af, Bv[nt], C[ml][nt], 0, 0, 0);
        }
    }
    prelu(A0v, m0); __syncthreads(); storeC(); __syncthreads();

    gemmK64(wsp + OA1F + (size_t)d * SZ_AH, b1 + d * HH);
    prelu(A1v, m1); __syncthreads(); storeC(); __syncthreads();

    gemmK64(wsp + OA2F + (size_t)d * SZ_AH, b2 + d * HH);
    prelu(A2v, m2);   // h2 stays in registers for the output dot

    // ---- output: out[n] = b3[d] + sum_h h2[h][n]*w3[h] (cross-wave via osb) ----
    f32x4 w3v[2];
    #pragma unroll
    for (int ml = 0; ml < 2; ++ml)
        w3v[ml] = *(const f32x4*)(W3 + d * HH + (2 * wv + ml) * 16 + hi * 4);
    #pragma unroll
    for (int nt = 0; nt < 4; ++nt) {
        float s = 0.0f;
        #pragma unroll
        for (int ml = 0; ml < 2; ++ml)
            #pragma unroll
            for (int r = 0; r < 4; ++r)
                s = fmaf(w3v[ml][r], C[ml][nt][r], s);
        s += __shfl_xor(s, 16);
        s += __shfl_xor(s, 32);
        if (hi == 0) osb[wv * 64 + nt * 16 + lo] = s;
    }
    __syncthreads();
    if (tid < 16) {
        const float b3v = b3[d];
        #pragma unroll
        for (int nt = 0; nt < 4; ++nt) {
            int n = w0 + nt * 16 + tid;
            if (n < NW)
                out[RES_OFF + ((size_t)b * NW + n) * DD + d] =
                    osb[nt * 16 + tid] + osb[64 + nt * 16 + tid] + b3v;
        }
    }

    // ================= backward =================
    // v2[h][n] = w3[h] * d2(h,n)  (own M-half; masks align with forward rows)
    #pragma unroll
    for (int ml = 0; ml < 2; ++ml)
        #pragma unroll
        for (int nt = 0; nt < 4; ++nt)
            #pragma unroll
            for (int r = 0; r < 4; ++r) {
                float dv = ((m2 >> (nt * 8 + ml * 4 + r)) & 1u) ? 1.0f : A2v;
                C[ml][nt][r] = w3v[ml][r] * dv;
            }
    __syncthreads(); storeC(); __syncthreads();

    gemmK64(wsp + OA2T + (size_t)d * SZ_AH, nullptr);
    bwd_mask(A1v, m1); __syncthreads(); storeC(); __syncthreads();

    gemmK64(wsp + OA1T + (size_t)d * SZ_AH, nullptr);
    bwd_mask(A0v, m0); __syncthreads(); storeC(); __syncthreads();

    // ---- g = W0^T-frag @ v0 : wave w takes m-tile mt=w (f rows 16w..16w+15) ----
    f32x4 G[4];
    {
        const _Float16* apk = wsp + OA0T + (size_t)d * SZ_A0T;
        #pragma unroll
        for (int nt = 0; nt < 4; ++nt) {
            G[nt][0] = 0.f; G[nt][1] = 0.f; G[nt][2] = 0.f; G[nt][3] = 0.f;
        }
        #pragma unroll
        for (int kc = 0; kc < 2; ++kc) {
            half8 Bv[4];
            #pragma unroll
            for (int nt = 0; nt < 4; ++nt)
                Bv[nt] = *(const half8*)&Xs[swb(nt * 16 + lo, kc * 64 + hi * 16)];
            half8 af = *(const half8*)(apk + (size_t)((wv * 2 + kc) * 64 + t) * 8);
            #pragma unroll
            for (int nt = 0; nt < 4; ++nt)
                G[nt] = __builtin_amdgcn_mfma_f32_16x16x32_f16(af, Bv[nt], G[nt], 0, 0, 0);
        }
    }

    if (wv == 0) {
        // hist_jac: f = hi*4 + r (rows 0..15), n = nt*16 + lo
        #pragma unroll
        for (int nt = 0; nt < 4; ++nt) {
            int n = w0 + nt * 16 + lo;
            if (n < NW)
                *(f32x4*)(out + HJ_OFF + ((size_t)d * NTOT + (size_t)b * NW + n) * 16
                          + hi * 4) = G[nt];
        }
    } else {
        // log|g[16]|: f=16 is row 0 of wave1's tile -> lanes hi==0, reg 0
        float ld = 0.0f;
        if (hi == 0) {
            #pragma unroll
            for (int nt = 0; nt < 4; ++nt) {
                int n = w0 + nt * 16 + lo;
                if (n < NW) ld += __logf(fabsf(G[nt][0]));
            }
        }
        #pragma unroll
        for (int off = 32; off > 0; off >>= 1) ld += __shfl_down(ld, off);
        if (t == 0) partials[(b * DD + d) * GX + bx] = ld;
    }
}

__global__ void reduce_log(const float* __restrict__ partials, float* __restrict__ out)
{
    const int b = threadIdx.x;   // 64 threads
    float s = 0.0f;
    #pragma unroll
    for (int i = 0; i < DD * GX; ++i) s += partials[b * (DD * GX) + i];
    out[LOG_OFF + b] = s;
}

extern "C" void kernel_launch(void* const* d_in, const int* in_sizes, int n_in,
                              void* d_out, int out_size, void* d_ws, size_t ws_size,
                              hipStream_t stream)
{
    const float* x  = (const float*)d_in[0];
    const float* W0 = (const float*)d_in[1];
    const float* b0 = (const float*)d_in[2];
    const float* a0 = (const float*)d_in[3];
    const float* W1 = (const float*)d_in[4];
    const float* b1 = (const float*)d_in[5];
    const float* a1 = (const float*)d_in[6];
    const float* W2 = (const float*)d_in[7];
    const float* b2 = (const float*)d_in[8];
    const float* a2 = (const float*)d_in[9];
    const float* W3 = (const float*)d_in[10];
    const float* b3 = (const float*)d_in[11];

    float*     out      = (float*)d_out;
    _Float16*  wsp      = (_Float16*)d_ws;
    float*     partials = (float*)((char*)d_ws + (size_t)WTOT * 2);  // 8192 floats

    setup_weights<<<160, 1024, 0, stream>>>(W0, W1, W2, wsp);

    dim3 grid(GX, BB, DD);
    fused_mlp<<<grid, 128, 0, stream>>>(x, b0, a0, b1, a1, b2, a2, W3, b3,
                                        wsp, out, partials);
    reduce_log<<<1, BB, 0, stream>>>(partials, out);
}

// Round 9
// 73.104 us; speedup vs baseline: 1.1313x; 1.1313x over previous
//
#include <hip/hip_runtime.h>
#include <cmath>

typedef _Float16 half8 __attribute__((ext_vector_type(8)));
typedef float f32x4 __attribute__((ext_vector_type(4)));

namespace {
constexpr int BB   = 64;
constexpr int TT   = 1002;
constexpr int DD   = 8;
constexpr int HH   = 64;
constexpr int LAGS = 2;
constexpr int NW   = TT - LAGS;          // 1000
constexpr int FIN  = LAGS * DD + 1;      // 17
constexpr int NTOT = BB * NW;            // 64000
constexpr int GX   = (NW + 63) / 64;     // 16 window-tiles
constexpr int TPB  = 4;                  // tiles per block (loop)

// output layout (flat, return order)
constexpr int RES_OFF = 0;
constexpr int LOG_OFF = NTOT * DD;
constexpr int HJ_OFF  = LOG_OFF + BB;

// prepacked A-fragment arrays in d_ws (f16 units).
// A-frag layout per (mt,kc): lane holds A[m][k], m = mt*16 + (lane&15),
// k = kc*32 + (lane>>4)*8 + j, j=0..7  -> [mt][kc][lane][8] contiguous.
constexpr int SZ_A0F = 4 * 1 * 64 * 8;   // fwd L0: A[h][f], K=32 (pad f>=17 -> 0)
constexpr int SZ_AH  = 4 * 2 * 64 * 8;   // 64x64 matrices, K=64
constexpr int SZ_A0T = 2 * 2 * 64 * 8;   // g-step: A[f][h], M=32 (pad f>=17 -> 0)
constexpr int OA0F = 0;
constexpr int OA1F = OA0F + DD * SZ_A0F; // W1 fwd
constexpr int OA2F = OA1F + DD * SZ_AH;  // W2 fwd
constexpr int OA2T = OA2F + DD * SZ_AH;  // W2^T (v1 step)
constexpr int OA1T = OA2T + DD * SZ_AH;  // W1^T (v0 step)
constexpr int OA0T = OA1T + DD * SZ_AH;  // W0^T (g step)
constexpr int WTOT = OA0T + DD * SZ_A0T; // 163840 f16 = 320 KB
}

// packed f32->f16 conversion (v_cvt_pkrtz_f16_f32): 1 inst / 2 elements.
// NOTE: builtin returns __fp16x2 -> bit_cast straight to u32 (round-8 fix).
__device__ __forceinline__ unsigned int pku(float a, float b) {
    return __builtin_bit_cast(unsigned int, __builtin_amdgcn_cvt_pkrtz(a, b));
}

// Prepack all weights into per-lane MFMA A-fragments (f16).
__global__ void setup_weights(const float* __restrict__ W0, const float* __restrict__ W1,
                              const float* __restrict__ W2, _Float16* __restrict__ wsp)
{
    for (int i = blockIdx.x * blockDim.x + threadIdx.x; i < WTOT;
         i += gridDim.x * blockDim.x) {
        float val;
        if (i < OA1F) {          // A0F: A[m=h][k=f] = W0[d,m,k], K=32 padded
            int j = i - OA0F, d = j / SZ_A0F, r = j % SZ_A0F;
            int mt = r / 512, r2 = r % 512, lane = r2 / 8, jj = r2 % 8;
            int m = mt * 16 + (lane & 15), k = (lane >> 4) * 8 + jj;
            val = (k < FIN) ? W0[((size_t)d * HH + m) * FIN + k] : 0.0f;
        } else if (i < OA2F) {   // A1F: A[m][k] = W1[d,m,k]
            int j = i - OA1F, d = j / SZ_AH, r = j % SZ_AH;
            int mt = r / 1024, r2 = r % 1024, kc = r2 / 512, r3 = r2 % 512;
            int lane = r3 / 8, jj = r3 % 8;
            int m = mt * 16 + (lane & 15), k = kc * 32 + (lane >> 4) * 8 + jj;
            val = W1[((size_t)d * HH + m) * HH + k];
        } else if (i < OA2T) {   // A2F: A[m][k] = W2[d,m,k]
            int j = i - OA2F, d = j / SZ_AH, r = j % SZ_AH;
            int mt = r / 1024, r2 = r % 1024, kc = r2 / 512, r3 = r2 % 512;
            int lane = r3 / 8, jj = r3 % 8;
            int m = mt * 16 + (lane & 15), k = kc * 32 + (lane >> 4) * 8 + jj;
            val = W2[((size_t)d * HH + m) * HH + k];
        } else if (i < OA1T) {   // A2T: A[m=h'][k=g] = W2[d,k,m]
            int j = i - OA2T, d = j / SZ_AH, r = j % SZ_AH;
            int mt = r / 1024, r2 = r % 1024, kc = r2 / 512, r3 = r2 % 512;
            int lane = r3 / 8, jj = r3 % 8;
            int m = mt * 16 + (lane & 15), k = kc * 32 + (lane >> 4) * 8 + jj;
            val = W2[((size_t)d * HH + k) * HH + m];
        } else if (i < OA0T) {   // A1T: A[m=h][k=h'] = W1[d,k,m]
            int j = i - OA1T, d = j / SZ_AH, r = j % SZ_AH;
            int mt = r / 1024, r2 = r % 1024, kc = r2 / 512, r3 = r2 % 512;
            int lane = r3 / 8, jj = r3 % 8;
            int m = mt * 16 + (lane & 15), k = kc * 32 + (lane >> 4) * 8 + jj;
            val = W1[((size_t)d * HH + k) * HH + m];
        } else {                 // A0T: A[m=f][k=h] = W0[d,k,m], M=32 padded
            int j = i - OA0T, d = j / SZ_A0T, r = j % SZ_A0T;
            int mt = r / 1024, r2 = r % 1024, kc = r2 / 512, r3 = r2 % 512;
            int lane = r3 / 8, jj = r3 % 8;
            int m = mt * 16 + (lane & 15), k = kc * 32 + (lane >> 4) * 8 + jj;
            val = (m < FIN) ? W0[((size_t)d * HH + k) * FIN + m] : 0.0f;
        }
        wsp[i] = (_Float16)val;
    }
}

// swizzled LDS byte address for activation tile X[n][k] (rows 128B):
// XOR bits 4-6 with (n&7) -> b128 reads and b64 writes are ~2-way (free).
__device__ __forceinline__ int swb(int n, int byteoff) {
    return n * 128 + (byteoff ^ ((n & 7) << 4));
}

// Persistent-weights 4-wave blocks: block = (tile-group, b, d), 256 threads.
// Wave w owns output rows h = 16w..16w+15 of every GEMM (C[4] f32x4 = 16 VGPR,
// 16-bit masks). All weight fragments + biases hoisted to registers BEFORE a
// 4-iteration loop over window tiles -> zero weight loads/addressing in-loop.
// Round-7 evidence: total VALU (~49us worth) + stage latency at 6 waves/CU
// were the binding constraints.
__global__ __launch_bounds__(256, 4) void fused_mlp(
    const float* __restrict__ x,
    const float* __restrict__ b0, const float* __restrict__ a0,
    const float* __restrict__ b1, const float* __restrict__ a1,
    const float* __restrict__ b2, const float* __restrict__ a2,
    const float* __restrict__ W3, const float* __restrict__ b3,
    const _Float16* __restrict__ wsp,
    float* __restrict__ out, float* __restrict__ partials)
{
    const int b   = blockIdx.y;    // 0..BB-1
    const int d   = blockIdx.z;    // 0..DD-1
    const int tid = threadIdx.x;
    const int wv  = __builtin_amdgcn_readfirstlane(tid >> 6);  // 0..3 (SGPR)
    const int t   = tid & 63;
    const int hi  = t >> 4, lo = t & 15;

    __shared__ __align__(16) unsigned char Xs[64 * 128];  // X[n][k] f16, swizzled
    __shared__ float osb[256];                            // cross-wave output partials

    // ---- hoist weights (M-quarter per wave) + biases into registers ----
    half8 wL0 = *(const half8*)(wsp + OA0F + (size_t)d * SZ_A0F + (size_t)(wv * 64 + t) * 8);
    half8 wL1[2], wL2[2], wT2[2], wT1[2];
    #pragma unroll
    for (int kc = 0; kc < 2; ++kc) {
        const size_t fo = (size_t)((wv * 2 + kc) * 64 + t) * 8;
        wL1[kc] = *(const half8*)(wsp + OA1F + (size_t)d * SZ_AH + fo);
        wL2[kc] = *(const half8*)(wsp + OA2F + (size_t)d * SZ_AH + fo);
        wT2[kc] = *(const half8*)(wsp + OA2T + (size_t)d * SZ_AH + fo);
        wT1[kc] = *(const half8*)(wsp + OA1T + (size_t)d * SZ_AH + fo);
    }
    half8 wG[2];
    if (wv < 2) {   // A0T has only 2 m-tiles (f rows 0..31); wave-uniform branch
        #pragma unroll
        for (int kc = 0; kc < 2; ++kc)
            wG[kc] = *(const half8*)(wsp + OA0T + (size_t)d * SZ_A0T
                                     + (size_t)((wv * 2 + kc) * 64 + t) * 8);
    }
    const f32x4 bb0 = *(const f32x4*)(b0 + d * HH + wv * 16 + hi * 4);
    const f32x4 bb1 = *(const f32x4*)(b1 + d * HH + wv * 16 + hi * 4);
    const f32x4 bb2 = *(const f32x4*)(b2 + d * HH + wv * 16 + hi * 4);
    const f32x4 w3v = *(const f32x4*)(W3 + d * HH + wv * 16 + hi * 4);
    const float A0v = a0[d], A1v = a1[d], A2v = a2[d], b3v = b3[d];

    f32x4 C[4];   // [nt]: row h = wv*16 + hi*4 + r, col n = nt*16 + lo

    // K=64 GEMM into C (B from LDS, A resident in regs)
    auto gemmK64 = [&](const half8* w, const f32x4* bias) {
        #pragma unroll
        for (int nt = 0; nt < 4; ++nt) {
            if (bias) C[nt] = *bias;
            else { C[nt][0] = 0.f; C[nt][1] = 0.f; C[nt][2] = 0.f; C[nt][3] = 0.f; }
        }
        #pragma unroll
        for (int kc = 0; kc < 2; ++kc) {
            half8 Bv[4];
            #pragma unroll
            for (int nt = 0; nt < 4; ++nt)
                Bv[nt] = *(const half8*)&Xs[swb(nt * 16 + lo, kc * 64 + hi * 16)];
            #pragma unroll
            for (int nt = 0; nt < 4; ++nt)
                C[nt] = __builtin_amdgcn_mfma_f32_16x16x32_f16(w[kc], Bv[nt], C[nt], 0, 0, 0);
        }
    };

    // store this wave's 16-row C slice (f16, pkrtz) into the activation tile
    auto storeC = [&]() {
        #pragma unroll
        for (int nt = 0; nt < 4; ++nt) {
            uint2 pk;
            pk.x = pku(C[nt][0], C[nt][1]);
            pk.y = pku(C[nt][2], C[nt][3]);
            *(uint2*)&Xs[swb(nt * 16 + lo, wv * 32 + hi * 8)] = pk;
        }
    };

    // ---- loop over window tiles ----
    for (int it = 0; it < TPB; ++it) {
        const int bx = blockIdx.x * TPB + it;
        const int w0 = bx * 64;

        // build B0 rows (threads 0..63, one row each)
        if (tid < 64) {
            const int w = min(w0 + tid, NW - 1);
            const float* xr = x + ((size_t)b * TT + w) * DD;
            f32x4 x0 = *(const f32x4*)(xr + 0);
            f32x4 x1 = *(const f32x4*)(xr + 4);
            f32x4 x2 = *(const f32x4*)(xr + 8);
            f32x4 x3 = *(const f32x4*)(xr + 12);
            float xl = xr[2 * DD + d];
            uint4 q0, q1, qz;
            q0.x = pku(x0[0], x0[1]); q0.y = pku(x0[2], x0[3]);
            q0.z = pku(x1[0], x1[1]); q0.w = pku(x1[2], x1[3]);
            q1.x = pku(x2[0], x2[1]); q1.y = pku(x2[2], x2[3]);
            q1.z = pku(x3[0], x3[1]); q1.w = pku(x3[2], x3[3]);
            qz.x = pku(xl, 0.f); qz.y = 0u; qz.z = 0u; qz.w = 0u;
            *(uint4*)&Xs[swb(tid, 0)]  = q0;
            *(uint4*)&Xs[swb(tid, 16)] = q1;
            *(uint4*)&Xs[swb(tid, 32)] = qz;
            uint4 zz; zz.x = 0u; zz.y = 0u; zz.z = 0u; zz.w = 0u;
            *(uint4*)&Xs[swb(tid, 48)] = zz;
        }
        __syncthreads();

        unsigned int m0 = 0u, m1 = 0u, m2 = 0u;   // 16-bit masks: bit = nt*4 + r
        auto prelu = [&](float slope, unsigned int& mask) {
            #pragma unroll
            for (int nt = 0; nt < 4; ++nt)
                #pragma unroll
                for (int r = 0; r < 4; ++r) {
                    float z = C[nt][r];
                    if (z > 0.0f) mask |= 1u << (nt * 4 + r);
                    C[nt][r] = fmaxf(z, slope * z);  // slope=0.25 in [0,1]
                }
        };
        auto bwd_mask = [&](float slope, unsigned int mask) {
            #pragma unroll
            for (int nt = 0; nt < 4; ++nt)
                #pragma unroll
                for (int r = 0; r < 4; ++r)
                    if (!((mask >> (nt * 4 + r)) & 1u))
                        C[nt][r] *= slope;
        };

        // ---- layer 0: K=32 ----
        {
            #pragma unroll
            for (int nt = 0; nt < 4; ++nt) C[nt] = bb0;
            half8 Bv[4];
            #pragma unroll
            for (int nt = 0; nt < 4; ++nt)
                Bv[nt] = *(const half8*)&Xs[swb(nt * 16 + lo, hi * 16)];
            #pragma unroll
            for (int nt = 0; nt < 4; ++nt)
                C[nt] = __builtin_amdgcn_mfma_f32_16x16x32_f16(wL0, Bv[nt], C[nt], 0, 0, 0);
        }
        prelu(A0v, m0);
        __syncthreads(); storeC(); __syncthreads();

        gemmK64(wL1, &bb1);
        prelu(A1v, m1);
        __syncthreads(); storeC(); __syncthreads();

        gemmK64(wL2, &bb2);
        prelu(A2v, m2);

        // ---- output dot (this wave's 16 rows) + v2 init ----
        float osum[4];
        #pragma unroll
        for (int nt = 0; nt < 4; ++nt) {
            float s = 0.0f;
            #pragma unroll
            for (int r = 0; r < 4; ++r) s = fmaf(w3v[r], C[nt][r], s);
            s += __shfl_xor(s, 16);
            s += __shfl_xor(s, 32);
            osum[nt] = s;
        }
        if (hi == 0) {
            #pragma unroll
            for (int nt = 0; nt < 4; ++nt) osb[wv * 64 + nt * 16 + lo] = osum[nt];
        }
        // v2[h][n] = w3[h] * d2(h,n)
        #pragma unroll
        for (int nt = 0; nt < 4; ++nt)
            #pragma unroll
            for (int r = 0; r < 4; ++r) {
                float dv = ((m2 >> (nt * 4 + r)) & 1u) ? 1.0f : A2v;
                C[nt][r] = w3v[r] * dv;
            }
        __syncthreads();           // L2 tile reads done by all waves + osb visible
        storeC();                  // v2 -> tile
        if (tid < 16) {
            #pragma unroll
            for (int nt = 0; nt < 4; ++nt) {
                int n = w0 + nt * 16 + tid;
                if (n < NW)
                    out[RES_OFF + ((size_t)b * NW + n) * DD + d] =
                        osb[nt * 16 + tid] + osb[64 + nt * 16 + tid] +
                        osb[128 + nt * 16 + tid] + osb[192 + nt * 16 + tid] + b3v;
            }
        }
        __syncthreads();

        gemmK64(wT2, nullptr);
        bwd_mask(A1v, m1);
        __syncthreads(); storeC(); __syncthreads();

        gemmK64(wT1, nullptr);
        bwd_mask(A0v, m0);
        __syncthreads(); storeC(); __syncthreads();

        // ---- g = W0^T @ v0 : waves 0,1 only (f rows 0..31) ----
        if (wv < 2) {
            f32x4 G[4];
            #pragma unroll
            for (int nt = 0; nt < 4; ++nt) {
                G[nt][0] = 0.f; G[nt][1] = 0.f; G[nt][2] = 0.f; G[nt][3] = 0.f;
            }
            #pragma unroll
            for (int kc = 0; kc < 2; ++kc) {
                half8 Bv[4];
                #pragma unroll
                for (int nt = 0; nt < 4; ++nt)
                    Bv[nt] = *(const half8*)&Xs[swb(nt * 16 + lo, kc * 64 + hi * 16)];
                #pragma unroll
                for (int nt = 0; nt < 4; ++nt)
                    G[nt] = __builtin_amdgcn_mfma_f32_16x16x32_f16(wG[kc], Bv[nt], G[nt], 0, 0, 0);
            }
            if (wv == 0) {
                // hist_jac: f = hi*4 + r (0..15), n = nt*16 + lo
                #pragma unroll
                for (int nt = 0; nt < 4; ++nt) {
                    int n = w0 + nt * 16 + lo;
                    if (n < NW)
                        *(f32x4*)(out + HJ_OFF
                                  + ((size_t)d * NTOT + (size_t)b * NW + n) * 16
                                  + hi * 4) = G[nt];
                }
            } else {
                // log|g[16]|: f=16 -> local row 0 of wave1 (hi==0, reg 0)
                float ld = 0.0f;
                if (hi == 0) {
                    #pragma unroll
                    for (int nt = 0; nt < 4; ++nt) {
                        int n = w0 + nt * 16 + lo;
                        if (n < NW) ld += __logf(fabsf(G[nt][0]));
                    }
                }
                #pragma unroll
                for (int off = 32; off > 0; off >>= 1) ld += __shfl_down(ld, off);
                if (t == 0) partials[(b * DD + d) * GX + bx] = ld;
            }
        }
        __syncthreads();   // tile reads done before next iteration's staging
    }
}

__global__ void reduce_log(const float* __restrict__ partials, float* __restrict__ out)
{
    const int b = threadIdx.x;   // 64 threads
    float s = 0.0f;
    #pragma unroll
    for (int i = 0; i < DD * GX; ++i) s += partials[b * (DD * GX) + i];
    out[LOG_OFF + b] = s;
}

extern "C" void kernel_launch(void* const* d_in, const int* in_sizes, int n_in,
                              void* d_out, int out_size, void* d_ws, size_t ws_size,
                              hipStream_t stream)
{
    const float* x  = (const float*)d_in[0];
    const float* W0 = (const float*)d_in[1];
    const float* b0 = (const float*)d_in[2];
    const float* a0 = (const float*)d_in[3];
    const float* W1 = (const float*)d_in[4];
    const float* b1 = (const float*)d_in[5];
    const float* a1 = (const float*)d_in[6];
    const float* W2 = (const float*)d_in[7];
    const float* b2 = (const float*)d_in[8];
    const float* a2 = (const float*)d_in[9];
    const float* W3 = (const float*)d_in[10];
    const float* b3 = (const float*)d_in[11];

    float*     out      = (float*)d_out;
    _Float16*  wsp      = (_Float16*)d_ws;
    float*     partials = (float*)((char*)d_ws + (size_t)WTOT * 2);  // 8192 floats

    setup_weights<<<160, 1024, 0, stream>>>(W0, W1, W2, wsp);

    dim3 grid(GX / TPB, BB, DD);   // 4 x 64 x 8 = 2048 blocks x 4 waves
    fused_mlp<<<grid, 256, 0, stream>>>(x, b0, a0, b1, a1, b2, a2, W3, b3,
                                        wsp, out, partials);
    reduce_log<<<1, BB, 0, stream>>>(partials, out);
}